// Round 7
// baseline (429.142 us; speedup 1.0000x reference)
//
#include <hip/hip_runtime.h>
#include <hip/hip_bf16.h>
#include <stdint.h>

// ---------- types / helpers ----------
typedef __bf16 bf16x8_t __attribute__((ext_vector_type(8)));
typedef float f32x4_t __attribute__((ext_vector_type(4)));
typedef unsigned short ushort8_t __attribute__((ext_vector_type(8)));  // 16B aligned

__device__ __forceinline__ unsigned short f2bf(float f) {
    union { float f; uint32_t i; } v; v.f = f;
    uint32_t i = v.i + (((v.i >> 16) & 1u) + 0x7FFFu);   // RNE
    return (unsigned short)(i >> 16);
}

typedef const __attribute__((address_space(1))) void* gas_t;
typedef __attribute__((address_space(3))) void* las_t;
__device__ __forceinline__ void load_lds16(const unsigned short* g, unsigned short* l) {
    // async global->LDS DMA; LDS dest = wave-uniform base + lane*16B
    __builtin_amdgcn_global_load_lds((gas_t)g, (las_t)l, 16, 0, 0);
}

// ---------- problem constants ----------
#define BB   256
#define CC   3
#define HH   128
#define WW   128
#define PP   768        // C*K*K
#define HID  2048
#define LL   256
#define MM   16384      // B*GH*GW

// ---------- patchify: x f32 (B,C,H,W) -> patches bf16 (M,768), u16-view of out0 ----------
__global__ void patchify(const float* __restrict__ x,
                         unsigned short* __restrict__ patches) {
    int t = blockIdx.x * 256 + threadIdx.x;        // 1,572,864 threads, 8 elems each
    int e = t * 8;                                  // linear index into x
    int col = e & 127;                              // w (multiple of 8)
    int row = (e >> 7) & 127;                       // h
    int c   = (e >> 14) % 3;
    int b   = e / (128 * 128 * 3);
    int gh = row >> 4, kh = row & 15, gw = col >> 4, kw = col & 15;
    long po = (long)(b * 64 + gh * 8 + gw) * PP + c * 256 + kh * 16 + kw;
    float4 v0 = *(const float4*)(x + e);
    float4 v1 = *(const float4*)(x + e + 4);
    ushort8_t o;
    o[0] = f2bf(v0.x); o[1] = f2bf(v0.y); o[2] = f2bf(v0.z); o[3] = f2bf(v0.w);
    o[4] = f2bf(v1.x); o[5] = f2bf(v1.y); o[6] = f2bf(v1.z); o[7] = f2bf(v1.w);
    *(ushort8_t*)(patches + po) = o;
}

// ---------- 32x32-tiled transpose + cast: out bf16[c*R+r] = in f32[r*C+c] ----------
__global__ void transpose_k(const float* __restrict__ in,
                            unsigned short* __restrict__ out, int R, int C) {
    __shared__ unsigned short tile[32][34];
    int nbc = C >> 5;
    int tc = blockIdx.x % nbc, tr = blockIdx.x / nbc;
    int tx = threadIdx.x & 31, ty0 = threadIdx.x >> 5;   // 8 rows/pass
    int r0 = tr << 5, c0 = tc << 5;
    #pragma unroll
    for (int i = 0; i < 4; ++i) {
        int ty = ty0 + i * 8;
        tile[ty][tx] = f2bf(in[(long)(r0 + ty) * C + c0 + tx]);
    }
    __syncthreads();
    #pragma unroll
    for (int i = 0; i < 4; ++i) {
        int ty = ty0 + i * 8;
        out[(long)(c0 + ty) * R + r0 + tx] = tile[tx][ty];
    }
}

// ---------- GEMM: C(rows x N) = act(A(rows x K) @ Bt(N x K)^T + bias f32) ----------
// Round-7: m201 geometry. tile 256x256, BK=64, 512 threads = 8 waves 2M x 4N,
// per-wave 128x64 output (43.7 FLOP/LDS-byte vs 32 at 64x64 — the R3/R5/R6
// LDS-BW ceiling). LDS 128 KiB: A[2dbuf][2half][128x64] + B same. 4 phases
// per K-tile t (quadrants of the wave tile, K=64 each):
//   ph1: ds_read af[i0-3]x2k (8) + bfA[j0-1]x2k (4);        BAR; 16 MFMA; BAR
//   ph2: ds_read bfB[j2-3]x2k (4);                           BAR; 16 MFMA; BAR
//   ph3: ds_read af[i4-7]x2k (8); STAGE B(t+2) (4 gloads);   BAR; 16 MFMA; BAR
//   ph4: STAGE A(t+2) (4 gloads); vmcnt(8);                  BAR; 16 MFMA; BAR
// WAR-safe by construction: B's last ds_read is ph2 -> B stages issue ph3
// (after the barrier ALL waves' ph2 MFMA consumed the reads); A's last read
// ph3 -> A stages ph4. Stage t+2 hits slot t&1 (being read) but only after
// its last reader. vmcnt(8) certifies tile t+1 (staged one full iter ago,
// ~1000+ cyc in flight); never drains except tail (vmcnt(0) at t=nt-2).
// Swizzle: 8 16B-groups/row; involution G' = G ^ ((G>>3)&7); frag rows are
// = fr (mod 8) so read XOR is lane-uniform: group (ks*4+quad)^(fr&7) ->
// 2-way bank alias (free). DMA dest linear + inverse-swz source (rule #21).
// ACT: 0=none 1=relu 2=sigmoid.  WMODE as before.
#define BMT 256
#define BNT 256
#define BKT 64

#define SBAR() do { __builtin_amdgcn_sched_barrier(0);                         \
                    __builtin_amdgcn_s_barrier();                              \
                    __builtin_amdgcn_sched_barrier(0); } while (0)

template <int ACT, int WMODE>
__global__ void __launch_bounds__(512, 2)
gemm_bt(const unsigned short* __restrict__ A, int lda,
        const unsigned short* __restrict__ Bt,
        const float* __restrict__ bias,
        unsigned short* __restrict__ C0u,
        float* __restrict__ C0f,
        float* __restrict__ C1f,
        int ldc, int Kd, int nbn, int m0) {
    // elems: A slots [d][h] at d*16384+h*8192; B same at +32768. 128 KiB.
    __shared__ __align__(16) unsigned short lds_buf[65536];
    const int nbm = gridDim.x / nbn;
    const int stripe = nbm >> 3;                 // bm rows per XCD
    const int xcd = blockIdx.x & 7;
    const int loc = blockIdx.x >> 3;
    const int bm = xcd * stripe + (loc % stripe);
    const int bn = loc / stripe;
    const int tid = threadIdx.x;
    const int wave = tid >> 6;
    const int lane = tid & 63;
    const int wr = wave >> 2;                    // 0..1 (M half, 128 rows)
    const int wc = wave & 3;                     // 0..3 (N quarter, 64 cols)
    const int fr = lane & 15;
    const int quad = lane >> 4;

    // staging source swizzle: phys 16B-group Gp (=tid within a 512-group
    // instruction block) holds logical group Gl = Gp ^ ((Gp>>3)&7).
    const int Gl = tid ^ ((tid >> 3) & 7);
    const int srow = Gl >> 3;                    // 0..63 (inst adds 64*i1)
    const int scol = (Gl & 7) << 3;              // k-elem 0..56

    const unsigned short* Ab = A + (long)bm * BMT * lda;
    const unsigned short* Bb = Bt + (long)bn * BNT * Kd;

    // fragment read offsets within a [128][64] half (elems):
    //   off = row*64 + ((ks*4+quad)^(row&7))*8 ; row%8 == fr%8 always
    const int gx0 = ((quad) ^ (fr & 7)) << 3;        // ks=0
    const int gx1 = ((4 | quad) ^ (fr & 7)) << 3;    // ks=1
    const int arow = fr << 6;                        // + i*1024
    const int brow = ((wc & 1) << 12) + (fr << 6);   // + j*1024

    f32x4_t acc[8][4];
    #pragma unroll
    for (int i = 0; i < 8; ++i)
        #pragma unroll
        for (int j = 0; j < 4; ++j)
            acc[i][j] = (f32x4_t){0.f, 0.f, 0.f, 0.f};

    const int nt = Kd / BKT;                     // 12 / 32 / 4 / 32

    // 4 gloads per matrix per tile: halves h0,h1 x inst i1=0,1 (64 rows each)
    #define STAGE_A(kt, d) do {                                                \
        unsigned short* a0 = lds_buf + (d) * 16384;                            \
        const long ko_ = (long)(kt) * 64 + scol;                               \
        load_lds16(Ab + (long)(srow)       * lda + ko_, a0 + (wave << 9));     \
        load_lds16(Ab + (long)(srow + 64)  * lda + ko_, a0 + 4096 + (wave << 9));\
        load_lds16(Ab + (long)(srow + 128) * lda + ko_, a0 + 8192 + (wave << 9));\
        load_lds16(Ab + (long)(srow + 192) * lda + ko_, a0 + 12288 + (wave << 9));\
    } while (0)
    #define STAGE_B(kt, d) do {                                                \
        unsigned short* b0 = lds_buf + 32768 + (d) * 16384;                    \
        const long ko_ = (long)(kt) * 64 + scol;                               \
        load_lds16(Bb + (long)(srow)       * Kd + ko_, b0 + (wave << 9));      \
        load_lds16(Bb + (long)(srow + 64)  * Kd + ko_, b0 + 4096 + (wave << 9));\
        load_lds16(Bb + (long)(srow + 128) * Kd + ko_, b0 + 8192 + (wave << 9));\
        load_lds16(Bb + (long)(srow + 192) * Kd + ko_, b0 + 12288 + (wave << 9));\
    } while (0)

    // prologue: tiles 0,1 (16 loads); certify tile 0 (leave tile 1 in flight)
    STAGE_B(0, 0); STAGE_A(0, 0);
    STAGE_B(1, 1); STAGE_A(1, 1);
    asm volatile("s_waitcnt vmcnt(8)" ::: "memory");
    SBAR();

    bf16x8_t af[4][2], bfA[2][2], bfB[2][2];
    for (int t = 0; t < nt; ++t) {
        const int d = t & 1;
        const unsigned short* Ah = lds_buf + d * 16384 + wr * 8192;
        const unsigned short* Bh = lds_buf + 32768 + d * 16384 + ((wc >> 1) << 13);

        // ---- ph1: Q(i0-3, j0-1) ----
        #pragma unroll
        for (int i = 0; i < 4; ++i) {
            af[i][0] = *(const bf16x8_t*)&Ah[arow + (i << 10) + gx0];
            af[i][1] = *(const bf16x8_t*)&Ah[arow + (i << 10) + gx1];
        }
        #pragma unroll
        for (int j = 0; j < 2; ++j) {
            bfA[j][0] = *(const bf16x8_t*)&Bh[brow + (j << 10) + gx0];
            bfA[j][1] = *(const bf16x8_t*)&Bh[brow + (j << 10) + gx1];
        }
        SBAR();
        __builtin_amdgcn_s_setprio(1);
        #pragma unroll
        for (int i = 0; i < 4; ++i)
            #pragma unroll
            for (int j = 0; j < 2; ++j) {
                acc[i][j] = __builtin_amdgcn_mfma_f32_16x16x32_bf16(
                    af[i][0], bfA[j][0], acc[i][j], 0, 0, 0);
                acc[i][j] = __builtin_amdgcn_mfma_f32_16x16x32_bf16(
                    af[i][1], bfA[j][1], acc[i][j], 0, 0, 0);
            }
        __builtin_amdgcn_s_setprio(0);
        SBAR();

        // ---- ph2: Q(i0-3, j2-3) ----
        #pragma unroll
        for (int j = 0; j < 2; ++j) {
            bfB[j][0] = *(const bf16x8_t*)&Bh[brow + ((j + 2) << 10) + gx0];
            bfB[j][1] = *(const bf16x8_t*)&Bh[brow + ((j + 2) << 10) + gx1];
        }
        SBAR();
        __builtin_amdgcn_s_setprio(1);
        #pragma unroll
        for (int i = 0; i < 4; ++i)
            #pragma unroll
            for (int j = 0; j < 2; ++j) {
                acc[i][j + 2] = __builtin_amdgcn_mfma_f32_16x16x32_bf16(
                    af[i][0], bfB[j][0], acc[i][j + 2], 0, 0, 0);
                acc[i][j + 2] = __builtin_amdgcn_mfma_f32_16x16x32_bf16(
                    af[i][1], bfB[j][1], acc[i][j + 2], 0, 0, 0);
            }
        __builtin_amdgcn_s_setprio(0);
        SBAR();

        // ---- ph3: Q(i4-7, j2-3); stage B(t+2) (B's last read was ph2) ----
        #pragma unroll
        for (int i = 0; i < 4; ++i) {
            af[i][0] = *(const bf16x8_t*)&Ah[arow + ((i + 4) << 10) + gx0];
            af[i][1] = *(const bf16x8_t*)&Ah[arow + ((i + 4) << 10) + gx1];
        }
        if (t + 2 < nt) STAGE_B(t + 2, d);
        SBAR();
        __builtin_amdgcn_s_setprio(1);
        #pragma unroll
        for (int i = 0; i < 4; ++i)
            #pragma unroll
            for (int j = 0; j < 2; ++j) {
                acc[i + 4][j + 2] = __builtin_amdgcn_mfma_f32_16x16x32_bf16(
                    af[i][0], bfB[j][0], acc[i + 4][j + 2], 0, 0, 0);
                acc[i + 4][j + 2] = __builtin_amdgcn_mfma_f32_16x16x32_bf16(
                    af[i][1], bfB[j][1], acc[i + 4][j + 2], 0, 0, 0);
            }
        __builtin_amdgcn_s_setprio(0);
        SBAR();

        // ---- ph4: Q(i4-7, j0-1); stage A(t+2) (A's last read was ph3) ----
        if (t + 2 < nt) {
            STAGE_A(t + 2, d);
            // certify tile t+1 (8 loads from prev iter); leave this iter's 8
            asm volatile("s_waitcnt vmcnt(8)" ::: "memory");
        } else if (t + 1 < nt) {
            // tail: only tile t+1's 8 outstanding
            asm volatile("s_waitcnt vmcnt(0)" ::: "memory");
        }
        SBAR();
        __builtin_amdgcn_s_setprio(1);
        #pragma unroll
        for (int i = 0; i < 4; ++i)
            #pragma unroll
            for (int j = 0; j < 2; ++j) {
                acc[i + 4][j] = __builtin_amdgcn_mfma_f32_16x16x32_bf16(
                    af[i][0], bfA[j][0], acc[i + 4][j], 0, 0, 0);
                acc[i + 4][j] = __builtin_amdgcn_mfma_f32_16x16x32_bf16(
                    af[i][1], bfA[j][1], acc[i + 4][j], 0, 0, 0);
            }
        __builtin_amdgcn_s_setprio(0);
        SBAR();
    }
    #undef STAGE_A
    #undef STAGE_B

    // epilogue — C/D layout: col = lane&15, row = (lane>>4)*4 + reg
    const int gcol0 = bn * BNT + (wc << 6);
    const int grow0 = bm * BMT + (wr << 7);
    #pragma unroll
    for (int j = 0; j < 4; ++j) {
        const int n = gcol0 + (j << 4) + fr;
        const float bv = bias[n];
        #pragma unroll
        for (int i = 0; i < 8; ++i) {
            #pragma unroll
            for (int r = 0; r < 4; ++r) {
                const int m = grow0 + (i << 4) + (quad << 2) + r;
                float v = acc[i][j][r] + bv;
                if (ACT == 1) v = fmaxf(v, 0.f);
                if (ACT == 2) v = 1.f / (1.f + __expf(-v));
                if (WMODE == 0) {
                    C0u[(long)m * ldc + n] = f2bf(v);
                } else if (WMODE == 1) {
                    const int gm = m0 + m;
                    C1f[((long)(gm >> 6) * 512 + n) * 64 + (gm & 63)] = v;
                    if (n < 256) C0u[(long)m * 256 + n] = f2bf(v);
                } else {
                    const int gm = m0 + m;
                    const int b = gm >> 6, g6 = gm & 63;
                    const int gh = g6 >> 3, gw = g6 & 7;
                    const int c = n >> 8, kh = (n >> 4) & 15, kw = n & 15;
                    const long o = (long)(b * 3 + c) * 16384
                                 + ((gh << 4) + kh) * 128 + (gw << 4) + kw;
                    C0f[o] = v;
                }
            }
        }
    }
}

// ---------- launch ----------
extern "C" void kernel_launch(void* const* d_in, const int* in_sizes, int n_in,
                              void* d_out, int out_size, void* d_ws, size_t ws_size,
                              hipStream_t stream) {
    const float* x      = (const float*)d_in[0];
    const float* w_enc1 = (const float*)d_in[1];
    const float* b_enc1 = (const float*)d_in[2];
    const float* w_enc2 = (const float*)d_in[3];
    const float* b_enc2 = (const float*)d_in[4];
    const float* w_dec1 = (const float*)d_in[5];
    const float* b_dec1 = (const float*)d_in[6];
    const float* w_dec2 = (const float*)d_in[7];
    const float* b_dec2 = (const float*)d_in[8];
    float* outf = (float*)d_out;                      // f32 output
    unsigned short* patches = (unsigned short*)d_out; // patches bf16 in out0 u16 view
    float* out_ml = outf + (long)MM * PP;             // f32 [12.58M, 20.97M)

    // Scratch: prefer d_ws (single 16384-row chunk); else fall back to x's dead
    // buffer with two 8192-row chunks in REVERSE order (round-9 proven).
    const size_t WT_ELEMS = 2048 * 768 + 512 * 2048 + 2048 * 256 + 768 * 2048;
    unsigned short* sb;
    long Mc;
    if (ws_size >= (WT_ELEMS + (size_t)MM * (LL + HID)) * 2) {
        sb = (unsigned short*)d_ws;  Mc = MM;         // 16384 rows, 1 chunk
    } else {
        sb = (unsigned short*)d_in[0]; Mc = 8192;     // x-buffer, 2 chunks
    }
    unsigned short* wT1 = sb;                         // 2048*768
    unsigned short* wT2 = wT1 + 2048 * 768;           // 512*2048
    unsigned short* wT3 = wT2 + 512 * 2048;           // 2048*256
    unsigned short* wT4 = wT3 + 2048 * 256;           // 768*2048
    unsigned short* mu  = wT4 + 768 * 2048;           // Mc*256
    unsigned short* he  = mu + Mc * LL;               // Mc*2048 (hd aliases he)

    patchify<<<6144, 256, 0, stream>>>(x, patches);

    transpose_k<<<(768 / 32) * (2048 / 32), 256, 0, stream>>>(w_enc1, wT1, 768, 2048);
    transpose_k<<<(2048 / 32) * (512 / 32), 256, 0, stream>>>(w_enc2, wT2, 2048, 512);
    transpose_k<<<(256 / 32) * (2048 / 32), 256, 0, stream>>>(w_dec1, wT3, 256, 2048);
    transpose_k<<<(2048 / 32) * (768 / 32), 256, 0, stream>>>(w_dec2, wT4, 2048, 768);

    const int nbm = (int)(Mc / BMT);   // 64 or 32, divisible by 8
    for (long m0 = MM - Mc; m0 >= 0; m0 -= Mc) {
        // he = relu(patches[m0:] @ w_enc1 + b_enc1)      Mc x 2048, K=768
        gemm_bt<1, 0><<<nbm * (HID / BNT), 512, 0, stream>>>(
            patches + m0 * PP, PP, wT1, b_enc1,
            he, nullptr, nullptr, HID, PP, HID / BNT, 0);
        // ml = he @ w_enc2 + b_enc2 -> out1 f32 (transposed) + compact bf16 mu
        gemm_bt<0, 1><<<nbm * (512 / BNT), 512, 0, stream>>>(
            he, HID, wT2, b_enc2,
            mu, nullptr, out_ml, 0, HID, 512 / BNT, (int)m0);
        // hd = relu(mu @ w_dec1 + b_dec1)                Mc x 2048, K=256
        gemm_bt<1, 0><<<nbm * (HID / BNT), 512, 0, stream>>>(
            mu, LL, wT3, b_dec1,
            he, nullptr, nullptr, HID, LL, HID / BNT, 0);
        // recon rows m0.. = sigmoid(hd @ w_dec2 + b_dec2) -> f32 scatter out0
        gemm_bt<2, 2><<<nbm * (PP / BNT), 512, 0, stream>>>(
            he, HID, wT4, b_dec2,
            nullptr, outf, nullptr, 0, HID, PP / BNT, (int)m0);
    }
}

// Round 8
// 373.246 us; speedup vs baseline: 1.1498x; 1.1498x over previous
//
#include <hip/hip_runtime.h>
#include <hip/hip_bf16.h>
#include <stdint.h>

// ---------- types / helpers ----------
typedef __bf16 bf16x8_t __attribute__((ext_vector_type(8)));
typedef float f32x4_t __attribute__((ext_vector_type(4)));
typedef unsigned short ushort8_t __attribute__((ext_vector_type(8)));  // 16B aligned

__device__ __forceinline__ unsigned short f2bf(float f) {
    union { float f; uint32_t i; } v; v.f = f;
    uint32_t i = v.i + (((v.i >> 16) & 1u) + 0x7FFFu);   // RNE
    return (unsigned short)(i >> 16);
}

typedef const __attribute__((address_space(1))) void* gas_t;
typedef __attribute__((address_space(3))) void* las_t;
__device__ __forceinline__ void load_lds16(const unsigned short* g, unsigned short* l) {
    // async global->LDS DMA; LDS dest = wave-uniform base + lane*16B
    __builtin_amdgcn_global_load_lds((gas_t)g, (las_t)l, 16, 0, 0);
}

// ---------- problem constants ----------
#define BB   256
#define CC   3
#define HH   128
#define WW   128
#define PP   768        // C*K*K
#define HID  2048
#define LL   256
#define MM   16384      // B*GH*GW

// ---------- patchify: x f32 (B,C,H,W) -> patches bf16 (M,768), u16-view of out0 ----------
__global__ void patchify(const float* __restrict__ x,
                         unsigned short* __restrict__ patches) {
    int t = blockIdx.x * 256 + threadIdx.x;        // 1,572,864 threads, 8 elems each
    int e = t * 8;                                  // linear index into x
    int col = e & 127;                              // w (multiple of 8)
    int row = (e >> 7) & 127;                       // h
    int c   = (e >> 14) % 3;
    int b   = e / (128 * 128 * 3);
    int gh = row >> 4, kh = row & 15, gw = col >> 4, kw = col & 15;
    long po = (long)(b * 64 + gh * 8 + gw) * PP + c * 256 + kh * 16 + kw;
    float4 v0 = *(const float4*)(x + e);
    float4 v1 = *(const float4*)(x + e + 4);
    ushort8_t o;
    o[0] = f2bf(v0.x); o[1] = f2bf(v0.y); o[2] = f2bf(v0.z); o[3] = f2bf(v0.w);
    o[4] = f2bf(v1.x); o[5] = f2bf(v1.y); o[6] = f2bf(v1.z); o[7] = f2bf(v1.w);
    *(ushort8_t*)(patches + po) = o;
}

// ---------- 32x32-tiled transpose + cast: out bf16[c*R+r] = in f32[r*C+c] ----------
__global__ void transpose_k(const float* __restrict__ in,
                            unsigned short* __restrict__ out, int R, int C) {
    __shared__ unsigned short tile[32][34];
    int nbc = C >> 5;
    int tc = blockIdx.x % nbc, tr = blockIdx.x / nbc;
    int tx = threadIdx.x & 31, ty0 = threadIdx.x >> 5;   // 8 rows/pass
    int r0 = tr << 5, c0 = tc << 5;
    #pragma unroll
    for (int i = 0; i < 4; ++i) {
        int ty = ty0 + i * 8;
        tile[ty][tx] = f2bf(in[(long)(r0 + ty) * C + c0 + tx]);
    }
    __syncthreads();
    #pragma unroll
    for (int i = 0; i < 4; ++i) {
        int ty = ty0 + i * 8;
        out[(long)(c0 + ty) * R + r0 + tx] = tile[tx][ty];
    }
}

// ---------- GEMM: C(rows x N) = act(A(rows x K) @ Bt(N x K)^T + bias f32) ----------
// R5 structure (best measured: G-big 74.9us, MfmaUtil 27.8%, 0 bank conflicts):
//   tile 256x128, BK=32, 512 threads = 8 waves as 4(M) x 2(N), per-wave 64x64.
//   LDS: TRIPLE-buffered (3 x 24 KiB = 72 KiB), prefetch distance 2
//   -> 2 blocks/CU (144 KiB), 4 waves/SIMD: two independent block pipelines
//   per CU overlap one block's LDS phase with the other's MFMA phase.
//   Race audit (3 buf, dist 2): STAGE(t+2) writes buf (t+2)%3 = (t-1)%3;
//   tile t-1's ds_reads completed before the barrier ending iter t-1. Safe.
//   vmcnt ledger: 3 loads/tile; vmcnt(3) at end of iter t certifies t+1,
//   leaves t+2 in flight. Never drains in steady state.
// NOTE (R6/R7 lesson): 4-phase barrier-heavy schedules and the 256x256 tile
// both REGRESSED (21%/12% MfmaUtil) — phase-locking without co-resident
// blocks serializes LDS reads against MFMA. Keep this structure.
// NOTE (floor): totals R3=378.157, R5=378.184 despite 26us GEMM delta ->
// bench total = max(~378.17us harness floor, our chain). Our chain ~300us.
// LDS swizzle: flat 16B-group involution G' = G ^ ((G>>3)&7). DMA dest linear,
//   global SOURCE pre-swizzled, frag reads swizzled (both-sides rule, rule #21).
// ACT: 0=none 1=relu 2=sigmoid.  WMODE as before.
#define BMT 256
#define BNT 128
#define BKT 32
#define LDS_TILE ((BMT + BNT) * BKT)   // 12288 elems = 24 KiB per buffer

template <int ACT, int WMODE>
__global__ void __launch_bounds__(512, 4)
gemm_bt(const unsigned short* __restrict__ A, int lda,
        const unsigned short* __restrict__ Bt,
        const float* __restrict__ bias,
        unsigned short* __restrict__ C0u,
        float* __restrict__ C0f,
        float* __restrict__ C1f,
        int ldc, int Kd, int nbn, int m0) {
    __shared__ __align__(16) unsigned short lds_buf[3 * LDS_TILE];   // 72 KiB
    const int nbm = gridDim.x / nbn;
    const int stripe = nbm >> 3;                 // bm rows per XCD
    const int xcd = blockIdx.x & 7;
    const int loc = blockIdx.x >> 3;
    const int bm = xcd * stripe + (loc % stripe);
    const int bn = loc / stripe;
    const int tid = threadIdx.x;
    const int wave = tid >> 6;
    const int lane = tid & 63;
    const int wr = wave >> 1;                    // 0..3 (M)
    const int wc = wave & 1;                     // 0..1 (N)
    const int fr = lane & 15;
    const int quad = lane >> 4;

    // staging: phys 16B-group Gp = inst_base + tid holds logical group
    // f(Gp) = Gp ^ ((Gp>>3)&7)  (involution; key bits 3..5 disjoint from
    // modified bits 0..2; inst bases 0/512/1024 groups are multiples of 512
    // so sr/sg are inst-invariant)
    const int Gl = tid ^ ((tid >> 3) & 7);
    const int sr = Gl >> 2;                      // logical row 0..127
    const int sg = (Gl & 3) << 3;                // logical col elem 0/8/16/24

    const unsigned short* Ab = A + (long)bm * BMT * lda;
    const unsigned short* Bb = Bt + (long)bn * BNT * Kd;

    // loop-invariant swizzled fragment offsets (elems): logical (row, quad)
    // -> phys group (row*4|quad) ^ ((row>>1)&7)
    int gA[4], gB[4];
    #pragma unroll
    for (int i = 0; i < 4; ++i) {
        const int r = (wr << 6) + (i << 4) + fr;
        gA[i] = ((((r << 2) | quad) ^ ((r >> 1) & 7)) << 3);
    }
    #pragma unroll
    for (int j = 0; j < 4; ++j) {
        const int r = (wc << 6) + (j << 4) + fr;
        gB[j] = ((((r << 2) | quad) ^ ((r >> 1) & 7)) << 3);
    }

    f32x4_t acc[4][4];
    #pragma unroll
    for (int i = 0; i < 4; ++i)
        #pragma unroll
        for (int j = 0; j < 4; ++j)
            acc[i][j] = (f32x4_t){0.f, 0.f, 0.f, 0.f};

    const int nt = Kd / BKT;

    // 3 vmem insts per wave per STAGE: A rows [0,128)+[128,256), B rows [0,128)
    #define STAGE(t, buf) do {                                                 \
        unsigned short* Al_ = (buf);                                           \
        unsigned short* Bl_ = Al_ + BMT * BKT;                                 \
        const long k0_ = (long)(t) * BKT;                                      \
        load_lds16(Ab + (long)sr * lda + k0_ + sg,         Al_ + (wave << 9)); \
        load_lds16(Ab + (long)(sr + 128) * lda + k0_ + sg,                     \
                   Al_ + 4096 + (wave << 9));                                  \
        load_lds16(Bb + (long)sr * Kd + k0_ + sg,          Bl_ + (wave << 9)); \
    } while (0)

    STAGE(0, lds_buf);
    STAGE(1, lds_buf + LDS_TILE);
    asm volatile("s_waitcnt vmcnt(3)" ::: "memory");   // tile 0 landed; tile 1 in flight
    __builtin_amdgcn_s_barrier();
    __builtin_amdgcn_sched_barrier(0);

    int rb = 0;            // read-buffer index  (t % 3)
    int sbx = 2;           // stage-buffer index ((t+2) % 3)
    for (int t = 0; t < nt; ++t) {
        if (t + 2 < nt) STAGE(t + 2, lds_buf + sbx * LDS_TILE);   // distance 2
        const unsigned short* Al = lds_buf + rb * LDS_TILE;
        const unsigned short* Bl = Al + BMT * BKT;
        bf16x8_t af[4], bfr[4];
        #pragma unroll
        for (int i = 0; i < 4; ++i) af[i] = *(const bf16x8_t*)&Al[gA[i]];
        #pragma unroll
        for (int j = 0; j < 4; ++j) bfr[j] = *(const bf16x8_t*)&Bl[gB[j]];
        __builtin_amdgcn_s_setprio(1);
        #pragma unroll
        for (int i = 0; i < 4; ++i)
            #pragma unroll
            for (int j = 0; j < 4; ++j)
                acc[i][j] = __builtin_amdgcn_mfma_f32_16x16x32_bf16(
                    af[i], bfr[j], acc[i][j], 0, 0, 0);
        __builtin_amdgcn_s_setprio(0);
        rb  = (rb == 2)  ? 0 : rb + 1;
        sbx = (sbx == 2) ? 0 : sbx + 1;
        if (t + 1 < nt) {
            // counted wait: leave (t+2)'s 3 loads in flight, certify (t+1)
            if (t + 2 < nt) asm volatile("s_waitcnt vmcnt(3)" ::: "memory");
            else            asm volatile("s_waitcnt vmcnt(0)" ::: "memory");
            __builtin_amdgcn_s_barrier();
            __builtin_amdgcn_sched_barrier(0);
        }
    }
    #undef STAGE

    // epilogue — C/D layout: col = lane&15, row = (lane>>4)*4 + reg
    const int gcol0 = bn * BNT + (wc << 6);
    const int grow0 = bm * BMT + (wr << 6);
    #pragma unroll
    for (int j = 0; j < 4; ++j) {
        const int n = gcol0 + (j << 4) + fr;
        const float bv = bias[n];
        #pragma unroll
        for (int i = 0; i < 4; ++i) {
            #pragma unroll
            for (int r = 0; r < 4; ++r) {
                const int m = grow0 + (i << 4) + (quad << 2) + r;
                float v = acc[i][j][r] + bv;
                if (ACT == 1) v = fmaxf(v, 0.f);
                if (ACT == 2) v = 1.f / (1.f + __expf(-v));
                if (WMODE == 0) {
                    C0u[(long)m * ldc + n] = f2bf(v);
                } else if (WMODE == 1) {
                    const int gm = m0 + m;
                    C1f[((long)(gm >> 6) * 512 + n) * 64 + (gm & 63)] = v;
                    if (n < 256) C0u[(long)m * 256 + n] = f2bf(v);
                } else {
                    const int gm = m0 + m;
                    const int b = gm >> 6, g6 = gm & 63;
                    const int gh = g6 >> 3, gw = g6 & 7;
                    const int c = n >> 8, kh = (n >> 4) & 15, kw = n & 15;
                    const long o = (long)(b * 3 + c) * 16384
                                 + ((gh << 4) + kh) * 128 + (gw << 4) + kw;
                    C0f[o] = v;
                }
            }
        }
    }
}

// ---------- launch ----------
extern "C" void kernel_launch(void* const* d_in, const int* in_sizes, int n_in,
                              void* d_out, int out_size, void* d_ws, size_t ws_size,
                              hipStream_t stream) {
    const float* x      = (const float*)d_in[0];
    const float* w_enc1 = (const float*)d_in[1];
    const float* b_enc1 = (const float*)d_in[2];
    const float* w_enc2 = (const float*)d_in[3];
    const float* b_enc2 = (const float*)d_in[4];
    const float* w_dec1 = (const float*)d_in[5];
    const float* b_dec1 = (const float*)d_in[6];
    const float* w_dec2 = (const float*)d_in[7];
    const float* b_dec2 = (const float*)d_in[8];
    float* outf = (float*)d_out;                      // f32 output
    unsigned short* patches = (unsigned short*)d_out; // patches bf16 in out0 u16 view
    float* out_ml = outf + (long)MM * PP;             // f32 [12.58M, 20.97M)

    // Scratch: prefer d_ws (single 16384-row chunk); else fall back to x's dead
    // buffer with two 8192-row chunks in REVERSE order (round-9 proven).
    const size_t WT_ELEMS = 2048 * 768 + 512 * 2048 + 2048 * 256 + 768 * 2048;
    unsigned short* sb;
    long Mc;
    if (ws_size >= (WT_ELEMS + (size_t)MM * (LL + HID)) * 2) {
        sb = (unsigned short*)d_ws;  Mc = MM;         // 16384 rows, 1 chunk
    } else {
        sb = (unsigned short*)d_in[0]; Mc = 8192;     // x-buffer, 2 chunks
    }
    unsigned short* wT1 = sb;                         // 2048*768
    unsigned short* wT2 = wT1 + 2048 * 768;           // 512*2048
    unsigned short* wT3 = wT2 + 512 * 2048;           // 2048*256
    unsigned short* wT4 = wT3 + 2048 * 256;           // 768*2048
    unsigned short* mu  = wT4 + 768 * 2048;           // Mc*256
    unsigned short* he  = mu + Mc * LL;               // Mc*2048 (hd aliases he)

    patchify<<<6144, 256, 0, stream>>>(x, patches);

    transpose_k<<<(768 / 32) * (2048 / 32), 256, 0, stream>>>(w_enc1, wT1, 768, 2048);
    transpose_k<<<(2048 / 32) * (512 / 32), 256, 0, stream>>>(w_enc2, wT2, 2048, 512);
    transpose_k<<<(256 / 32) * (2048 / 32), 256, 0, stream>>>(w_dec1, wT3, 256, 2048);
    transpose_k<<<(2048 / 32) * (768 / 32), 256, 0, stream>>>(w_dec2, wT4, 2048, 768);

    const int nbm = (int)(Mc / BMT);   // 64 or 32, divisible by 8
    for (long m0 = MM - Mc; m0 >= 0; m0 -= Mc) {
        // he = relu(patches[m0:] @ w_enc1 + b_enc1)      Mc x 2048, K=768
        gemm_bt<1, 0><<<nbm * (HID / BNT), 512, 0, stream>>>(
            patches + m0 * PP, PP, wT1, b_enc1,
            he, nullptr, nullptr, HID, PP, HID / BNT, 0);
        // ml = he @ w_enc2 + b_enc2 -> out1 f32 (transposed) + compact bf16 mu
        gemm_bt<0, 1><<<nbm * (512 / BNT), 512, 0, stream>>>(
            he, HID, wT2, b_enc2,
            mu, nullptr, out_ml, 0, HID, 512 / BNT, (int)m0);
        // hd = relu(mu @ w_dec1 + b_dec1)                Mc x 2048, K=256
        gemm_bt<1, 0><<<nbm * (HID / BNT), 512, 0, stream>>>(
            mu, LL, wT3, b_dec1,
            he, nullptr, nullptr, HID, LL, HID / BNT, 0);
        // recon rows m0.. = sigmoid(hd @ w_dec2 + b_dec2) -> f32 scatter out0
        gemm_bt<2, 2><<<nbm * (PP / BNT), 512, 0, stream>>>(
            he, HID, wT4, b_dec2,
            nullptr, outf, nullptr, 0, HID, PP / BNT, (int)m0);
    }
}

// Round 9
// 349.325 us; speedup vs baseline: 1.2285x; 1.0685x over previous
//
#include <hip/hip_runtime.h>
#include <hip/hip_bf16.h>
#include <stdint.h>

// ---------- types / helpers ----------
typedef __bf16 bf16x8_t __attribute__((ext_vector_type(8)));
typedef float f32x4_t __attribute__((ext_vector_type(4)));
typedef unsigned short ushort8_t __attribute__((ext_vector_type(8)));  // 16B aligned

__device__ __forceinline__ unsigned short f2bf(float f) {
    union { float f; uint32_t i; } v; v.f = f;
    uint32_t i = v.i + (((v.i >> 16) & 1u) + 0x7FFFu);   // RNE
    return (unsigned short)(i >> 16);
}

typedef const __attribute__((address_space(1))) void* gas_t;
typedef __attribute__((address_space(3))) void* las_t;
__device__ __forceinline__ void load_lds16(const unsigned short* g, unsigned short* l) {
    // async global->LDS DMA; LDS dest = wave-uniform base + lane*16B
    __builtin_amdgcn_global_load_lds((gas_t)g, (las_t)l, 16, 0, 0);
}

// ---------- problem constants ----------
#define BB   256
#define CC   3
#define HH   128
#define WW   128
#define PP   768        // C*K*K
#define HID  2048
#define LL   256
#define MM   16384      // B*GH*GW

// ---------- patchify: x f32 (B,C,H,W) -> patches bf16 (M,768), u16-view of out0 ----------
__global__ void patchify(const float* __restrict__ x,
                         unsigned short* __restrict__ patches) {
    int t = blockIdx.x * 256 + threadIdx.x;        // 1,572,864 threads, 8 elems each
    int e = t * 8;                                  // linear index into x
    int col = e & 127;                              // w (multiple of 8)
    int row = (e >> 7) & 127;                       // h
    int c   = (e >> 14) % 3;
    int b   = e / (128 * 128 * 3);
    int gh = row >> 4, kh = row & 15, gw = col >> 4, kw = col & 15;
    long po = (long)(b * 64 + gh * 8 + gw) * PP + c * 256 + kh * 16 + kw;
    float4 v0 = *(const float4*)(x + e);
    float4 v1 = *(const float4*)(x + e + 4);
    ushort8_t o;
    o[0] = f2bf(v0.x); o[1] = f2bf(v0.y); o[2] = f2bf(v0.z); o[3] = f2bf(v0.w);
    o[4] = f2bf(v1.x); o[5] = f2bf(v1.y); o[6] = f2bf(v1.z); o[7] = f2bf(v1.w);
    *(ushort8_t*)(patches + po) = o;
}

// ---------- 32x32-tiled transpose + cast: out bf16[c*R+r] = in f32[r*C+c] ----------
__global__ void transpose_k(const float* __restrict__ in,
                            unsigned short* __restrict__ out, int R, int C) {
    __shared__ unsigned short tile[32][34];
    int nbc = C >> 5;
    int tc = blockIdx.x % nbc, tr = blockIdx.x / nbc;
    int tx = threadIdx.x & 31, ty0 = threadIdx.x >> 5;   // 8 rows/pass
    int r0 = tr << 5, c0 = tc << 5;
    #pragma unroll
    for (int i = 0; i < 4; ++i) {
        int ty = ty0 + i * 8;
        tile[ty][tx] = f2bf(in[(long)(r0 + ty) * C + c0 + tx]);
    }
    __syncthreads();
    #pragma unroll
    for (int i = 0; i < 4; ++i) {
        int ty = ty0 + i * 8;
        out[(long)(c0 + ty) * R + r0 + tx] = tile[tx][ty];
    }
}

// ---------- GEMM: C(rows x N) = act(A(rows x K) @ Bt(N x K)^T + bias f32) ----------
// R5 structure (best measured: G-big 74.9us, MfmaUtil 27.8%, 0 bank conflicts):
//   tile 256x128, BK=32, 512 threads = 8 waves as 4(M) x 2(N), per-wave 64x64.
//   LDS: TRIPLE-buffered (3 x 24 KiB = 72 KiB), prefetch distance 2
//   -> 2 blocks/CU, 4 waves/SIMD: two independent block pipelines per CU.
//   vmcnt ledger: 3 loads/tile; vmcnt(3) at end of iter t certifies t+1.
// NOTE (R6/R7): 4-phase barrier schedules + 256x256 tile REGRESSED. Keep this.
// NOTE (R8): total noise +-5us; chain ~250us vs total ~373 -> ~120us harness
// reset chain; this round's G2 fix discriminates additive vs floor model.
// LDS swizzle: flat 16B-group involution G' = G ^ ((G>>3)&7) (rule #21).
// ACT: 0=none 1=relu 2=sigmoid.  WMODE as before.
#define BMT 256
#define BNT 128
#define BKT 32
#define LDS_TILE ((BMT + BNT) * BKT)   // 12288 elems = 24 KiB per buffer

template <int ACT, int WMODE>
__global__ void __launch_bounds__(512, 4)
gemm_bt(const unsigned short* __restrict__ A, int lda,
        const unsigned short* __restrict__ Bt,
        const float* __restrict__ bias,
        unsigned short* __restrict__ C0u,
        float* __restrict__ C0f,
        float* __restrict__ C1f,
        int ldc, int Kd, int nbn, int m0) {
    __shared__ __align__(16) unsigned short lds_buf[3 * LDS_TILE];   // 72 KiB
    const int nbm = gridDim.x / nbn;
    const int stripe = nbm >> 3;                 // bm rows per XCD
    const int xcd = blockIdx.x & 7;
    const int loc = blockIdx.x >> 3;
    const int bm = xcd * stripe + (loc % stripe);
    const int bn = loc / stripe;
    const int tid = threadIdx.x;
    const int wave = tid >> 6;
    const int lane = tid & 63;
    const int wr = wave >> 1;                    // 0..3 (M)
    const int wc = wave & 1;                     // 0..1 (N)
    const int fr = lane & 15;
    const int quad = lane >> 4;

    const int Gl = tid ^ ((tid >> 3) & 7);
    const int sr = Gl >> 2;                      // logical row 0..127
    const int sg = (Gl & 3) << 3;                // logical col elem 0/8/16/24

    const unsigned short* Ab = A + (long)bm * BMT * lda;
    const unsigned short* Bb = Bt + (long)bn * BNT * Kd;

    int gA[4], gB[4];
    #pragma unroll
    for (int i = 0; i < 4; ++i) {
        const int r = (wr << 6) + (i << 4) + fr;
        gA[i] = ((((r << 2) | quad) ^ ((r >> 1) & 7)) << 3);
    }
    #pragma unroll
    for (int j = 0; j < 4; ++j) {
        const int r = (wc << 6) + (j << 4) + fr;
        gB[j] = ((((r << 2) | quad) ^ ((r >> 1) & 7)) << 3);
    }

    f32x4_t acc[4][4];
    #pragma unroll
    for (int i = 0; i < 4; ++i)
        #pragma unroll
        for (int j = 0; j < 4; ++j)
            acc[i][j] = (f32x4_t){0.f, 0.f, 0.f, 0.f};

    const int nt = Kd / BKT;

    #define STAGE(t, buf) do {                                                 \
        unsigned short* Al_ = (buf);                                           \
        unsigned short* Bl_ = Al_ + BMT * BKT;                                 \
        const long k0_ = (long)(t) * BKT;                                      \
        load_lds16(Ab + (long)sr * lda + k0_ + sg,         Al_ + (wave << 9)); \
        load_lds16(Ab + (long)(sr + 128) * lda + k0_ + sg,                     \
                   Al_ + 4096 + (wave << 9));                                  \
        load_lds16(Bb + (long)sr * Kd + k0_ + sg,          Bl_ + (wave << 9)); \
    } while (0)

    STAGE(0, lds_buf);
    STAGE(1, lds_buf + LDS_TILE);
    asm volatile("s_waitcnt vmcnt(3)" ::: "memory");
    __builtin_amdgcn_s_barrier();
    __builtin_amdgcn_sched_barrier(0);

    int rb = 0;
    int sbx = 2;
    for (int t = 0; t < nt; ++t) {
        if (t + 2 < nt) STAGE(t + 2, lds_buf + sbx * LDS_TILE);
        const unsigned short* Al = lds_buf + rb * LDS_TILE;
        const unsigned short* Bl = Al + BMT * BKT;
        bf16x8_t af[4], bfr[4];
        #pragma unroll
        for (int i = 0; i < 4; ++i) af[i] = *(const bf16x8_t*)&Al[gA[i]];
        #pragma unroll
        for (int j = 0; j < 4; ++j) bfr[j] = *(const bf16x8_t*)&Bl[gB[j]];
        __builtin_amdgcn_s_setprio(1);
        #pragma unroll
        for (int i = 0; i < 4; ++i)
            #pragma unroll
            for (int j = 0; j < 4; ++j)
                acc[i][j] = __builtin_amdgcn_mfma_f32_16x16x32_bf16(
                    af[i], bfr[j], acc[i][j], 0, 0, 0);
        __builtin_amdgcn_s_setprio(0);
        rb  = (rb == 2)  ? 0 : rb + 1;
        sbx = (sbx == 2) ? 0 : sbx + 1;
        if (t + 1 < nt) {
            if (t + 2 < nt) asm volatile("s_waitcnt vmcnt(3)" ::: "memory");
            else            asm volatile("s_waitcnt vmcnt(0)" ::: "memory");
            __builtin_amdgcn_s_barrier();
            __builtin_amdgcn_sched_barrier(0);
        }
    }
    #undef STAGE

    const int gcol0 = bn * BNT + (wc << 6);
    const int grow0 = bm * BMT + (wr << 6);
    #pragma unroll
    for (int j = 0; j < 4; ++j) {
        const int n = gcol0 + (j << 4) + fr;
        const float bv = bias[n];
        #pragma unroll
        for (int i = 0; i < 4; ++i) {
            #pragma unroll
            for (int r = 0; r < 4; ++r) {
                const int m = grow0 + (i << 4) + (quad << 2) + r;
                float v = acc[i][j][r] + bv;
                if (ACT == 1) v = fmaxf(v, 0.f);
                if (ACT == 2) v = 1.f / (1.f + __expf(-v));
                if (WMODE == 0) {
                    C0u[(long)m * ldc + n] = f2bf(v);
                } else if (WMODE == 1) {
                    const int gm = m0 + m;
                    C1f[((long)(gm >> 6) * 512 + n) * 64 + (gm & 63)] = v;
                    if (n < 256) C0u[(long)m * 256 + n] = f2bf(v);
                } else {
                    const int gm = m0 + m;
                    const int b = gm >> 6, g6 = gm & 63;
                    const int gh = g6 >> 3, gw = g6 & 7;
                    const int c = n >> 8, kh = (n >> 4) & 15, kw = n & 15;
                    const long o = (long)(b * 3 + c) * 16384
                                 + ((gh << 4) + kh) * 128 + (gw << 4) + kw;
                    C0f[o] = v;
                }
            }
        }
    }
}

// ---------- 128x128-tile variant of the SAME R5 pipeline, for G2 only ----------
// G2 (N=512) at BNT=128 gives only 256 blocks = 1 block/CU -> the proven-slow
// no-overlap regime. 128x128 tile, 256 threads = 4 waves 2x2, per-wave 64x64
// (same FLOP/LDS-byte), triple-buffer 3x16KiB = 48 KiB -> 2+ blocks/CU at
// 512 blocks. Ledger: 4 gloads/tile (A rows 0-63,64-127; B same) -> steady
// vmcnt(4), tail vmcnt(0). Swizzle identical (inst bases multiple of 64
// 16B-groups keeps the involution inst-invariant).
template <int ACT, int WMODE>
__global__ void __launch_bounds__(256, 3)
gemm_bt128(const unsigned short* __restrict__ A, int lda,
           const unsigned short* __restrict__ Bt,
           const float* __restrict__ bias,
           unsigned short* __restrict__ C0u,
           float* __restrict__ C0f,
           float* __restrict__ C1f,
           int ldc, int Kd, int nbn, int m0) {
    __shared__ __align__(16) unsigned short lds_buf[3 * 8192];   // 48 KiB
    const int nbm = gridDim.x / nbn;
    const int stripe = nbm >> 3;
    const int xcd = blockIdx.x & 7;
    const int loc = blockIdx.x >> 3;
    const int bm = xcd * stripe + (loc % stripe);
    const int bn = loc / stripe;
    const int tid = threadIdx.x;
    const int wave = tid >> 6;                   // 0..3
    const int lane = tid & 63;
    const int wr = wave >> 1;                    // 0..1 (M)
    const int wc = wave & 1;                     // 0..1 (N)
    const int fr = lane & 15;
    const int quad = lane >> 4;

    const int Gl = tid ^ ((tid >> 3) & 7);       // tid 0..255 -> groups 0..255
    const int sr = Gl >> 2;                      // logical row 0..63
    const int sg = (Gl & 3) << 3;                // logical col elem 0/8/16/24

    const unsigned short* Ab = A + (long)bm * 128 * lda;
    const unsigned short* Bb = Bt + (long)bn * 128 * Kd;

    int gA[4], gB[4];
    #pragma unroll
    for (int i = 0; i < 4; ++i) {
        const int r = (wr << 6) + (i << 4) + fr;
        gA[i] = ((((r << 2) | quad) ^ ((r >> 1) & 7)) << 3);
    }
    #pragma unroll
    for (int j = 0; j < 4; ++j) {
        const int r = (wc << 6) + (j << 4) + fr;
        gB[j] = ((((r << 2) | quad) ^ ((r >> 1) & 7)) << 3);
    }

    f32x4_t acc[4][4];
    #pragma unroll
    for (int i = 0; i < 4; ++i)
        #pragma unroll
        for (int j = 0; j < 4; ++j)
            acc[i][j] = (f32x4_t){0.f, 0.f, 0.f, 0.f};

    const int nt = Kd / 32;

    // 4 gloads/tile: A rows [0,64)+[64,128), B rows [0,64)+[64,128)
    #define STAGE128(t, buf) do {                                              \
        unsigned short* Al_ = (buf);                                           \
        unsigned short* Bl_ = Al_ + 4096;                                      \
        const long k0_ = (long)(t) * 32;                                       \
        load_lds16(Ab + (long)sr * lda + k0_ + sg,        Al_ + (wave << 9));  \
        load_lds16(Ab + (long)(sr + 64) * lda + k0_ + sg,                      \
                   Al_ + 2048 + (wave << 9));                                  \
        load_lds16(Bb + (long)sr * Kd + k0_ + sg,         Bl_ + (wave << 9));  \
        load_lds16(Bb + (long)(sr + 64) * Kd + k0_ + sg,                       \
                   Bl_ + 2048 + (wave << 9));                                  \
    } while (0)

    STAGE128(0, lds_buf);
    STAGE128(1, lds_buf + 8192);
    asm volatile("s_waitcnt vmcnt(4)" ::: "memory");
    __builtin_amdgcn_s_barrier();
    __builtin_amdgcn_sched_barrier(0);

    int rb = 0;
    int sbx = 2;
    for (int t = 0; t < nt; ++t) {
        if (t + 2 < nt) STAGE128(t + 2, lds_buf + sbx * 8192);
        const unsigned short* Al = lds_buf + rb * 8192;
        const unsigned short* Bl = Al + 4096;
        bf16x8_t af[4], bfr[4];
        #pragma unroll
        for (int i = 0; i < 4; ++i) af[i] = *(const bf16x8_t*)&Al[gA[i]];
        #pragma unroll
        for (int j = 0; j < 4; ++j) bfr[j] = *(const bf16x8_t*)&Bl[gB[j]];
        __builtin_amdgcn_s_setprio(1);
        #pragma unroll
        for (int i = 0; i < 4; ++i)
            #pragma unroll
            for (int j = 0; j < 4; ++j)
                acc[i][j] = __builtin_amdgcn_mfma_f32_16x16x32_bf16(
                    af[i], bfr[j], acc[i][j], 0, 0, 0);
        __builtin_amdgcn_s_setprio(0);
        rb  = (rb == 2)  ? 0 : rb + 1;
        sbx = (sbx == 2) ? 0 : sbx + 1;
        if (t + 1 < nt) {
            if (t + 2 < nt) asm volatile("s_waitcnt vmcnt(4)" ::: "memory");
            else            asm volatile("s_waitcnt vmcnt(0)" ::: "memory");
            __builtin_amdgcn_s_barrier();
            __builtin_amdgcn_sched_barrier(0);
        }
    }
    #undef STAGE128

    const int gcol0 = bn * 128 + (wc << 6);
    const int grow0 = bm * 128 + (wr << 6);
    #pragma unroll
    for (int j = 0; j < 4; ++j) {
        const int n = gcol0 + (j << 4) + fr;
        const float bv = bias[n];
        #pragma unroll
        for (int i = 0; i < 4; ++i) {
            #pragma unroll
            for (int r = 0; r < 4; ++r) {
                const int m = grow0 + (i << 4) + (quad << 2) + r;
                float v = acc[i][j][r] + bv;
                if (ACT == 1) v = fmaxf(v, 0.f);
                if (ACT == 2) v = 1.f / (1.f + __expf(-v));
                if (WMODE == 0) {
                    C0u[(long)m * ldc + n] = f2bf(v);
                } else if (WMODE == 1) {
                    const int gm = m0 + m;
                    C1f[((long)(gm >> 6) * 512 + n) * 64 + (gm & 63)] = v;
                    if (n < 256) C0u[(long)m * 256 + n] = f2bf(v);
                } else {
                    const int gm = m0 + m;
                    const int b = gm >> 6, g6 = gm & 63;
                    const int gh = g6 >> 3, gw = g6 & 7;
                    const int c = n >> 8, kh = (n >> 4) & 15, kw = n & 15;
                    const long o = (long)(b * 3 + c) * 16384
                                 + ((gh << 4) + kh) * 128 + (gw << 4) + kw;
                    C0f[o] = v;
                }
            }
        }
    }
}

// ---------- launch ----------
extern "C" void kernel_launch(void* const* d_in, const int* in_sizes, int n_in,
                              void* d_out, int out_size, void* d_ws, size_t ws_size,
                              hipStream_t stream) {
    const float* x      = (const float*)d_in[0];
    const float* w_enc1 = (const float*)d_in[1];
    const float* b_enc1 = (const float*)d_in[2];
    const float* w_enc2 = (const float*)d_in[3];
    const float* b_enc2 = (const float*)d_in[4];
    const float* w_dec1 = (const float*)d_in[5];
    const float* b_dec1 = (const float*)d_in[6];
    const float* w_dec2 = (const float*)d_in[7];
    const float* b_dec2 = (const float*)d_in[8];
    float* outf = (float*)d_out;                      // f32 output
    unsigned short* patches = (unsigned short*)d_out; // patches bf16 in out0 u16 view
    float* out_ml = outf + (long)MM * PP;             // f32 [12.58M, 20.97M)

    const size_t WT_ELEMS = 2048 * 768 + 512 * 2048 + 2048 * 256 + 768 * 2048;
    unsigned short* sb;
    long Mc;
    if (ws_size >= (WT_ELEMS + (size_t)MM * (LL + HID)) * 2) {
        sb = (unsigned short*)d_ws;  Mc = MM;         // 16384 rows, 1 chunk
    } else {
        sb = (unsigned short*)d_in[0]; Mc = 8192;     // x-buffer, 2 chunks
    }
    unsigned short* wT1 = sb;                         // 2048*768
    unsigned short* wT2 = wT1 + 2048 * 768;           // 512*2048
    unsigned short* wT3 = wT2 + 512 * 2048;           // 2048*256
    unsigned short* wT4 = wT3 + 2048 * 256;           // 768*2048
    unsigned short* mu  = wT4 + 768 * 2048;           // Mc*256
    unsigned short* he  = mu + Mc * LL;               // Mc*2048 (hd aliases he)

    patchify<<<6144, 256, 0, stream>>>(x, patches);

    transpose_k<<<(768 / 32) * (2048 / 32), 256, 0, stream>>>(w_enc1, wT1, 768, 2048);
    transpose_k<<<(2048 / 32) * (512 / 32), 256, 0, stream>>>(w_enc2, wT2, 2048, 512);
    transpose_k<<<(256 / 32) * (2048 / 32), 256, 0, stream>>>(w_dec1, wT3, 256, 2048);
    transpose_k<<<(2048 / 32) * (768 / 32), 256, 0, stream>>>(w_dec2, wT4, 2048, 768);

    const int nbm = (int)(Mc / BMT);   // 64 or 32, divisible by 8
    for (long m0 = MM - Mc; m0 >= 0; m0 -= Mc) {
        // he = relu(patches[m0:] @ w_enc1 + b_enc1)      Mc x 2048, K=768
        gemm_bt<1, 0><<<nbm * (HID / BNT), 512, 0, stream>>>(
            patches + m0 * PP, PP, wT1, b_enc1,
            he, nullptr, nullptr, HID, PP, HID / BNT, 0);
        // ml = he @ w_enc2 + b_enc2 -> out1 f32 (transposed) + compact bf16 mu
        // 128x128 variant: (Mc/128)*(512/128) blocks = 512 -> 2 blocks/CU
        gemm_bt128<0, 1><<<(int)(Mc / 128) * (512 / 128), 256, 0, stream>>>(
            he, HID, wT2, b_enc2,
            mu, nullptr, out_ml, 0, HID, 512 / 128, (int)m0);
        // hd = relu(mu @ w_dec1 + b_dec1)                Mc x 2048, K=256
        gemm_bt<1, 0><<<nbm * (HID / BNT), 512, 0, stream>>>(
            mu, LL, wT3, b_dec1,
            he, nullptr, nullptr, HID, LL, HID / BNT, 0);
        // recon rows m0.. = sigmoid(hd @ w_dec2 + b_dec2) -> f32 scatter out0
        gemm_bt<2, 2><<<nbm * (PP / BNT), 512, 0, stream>>>(
            he, HID, wT4, b_dec2,
            nullptr, outf, nullptr, 0, HID, PP / BNT, (int)m0);
    }
}